// Round 3
// baseline (138.394 us; speedup 1.0000x reference)
//
#include <hip/hip_runtime.h>
#include <stdint.h>

#define TOK 256
#define IN_F 4096
#define OUT_F 4096
#define N_OUT 32
#define BN 16
#define TILE_A 16384   // one kstep A tile: 256 rows x 64 B (swizzled chunks)

typedef int v4i __attribute__((ext_vector_type(4)));

typedef const __attribute__((address_space(1))) void cg_void;
typedef __attribute__((address_space(3))) void lds_void;

__device__ __forceinline__ void gll16(const void* g, void* l) {
    __builtin_amdgcn_global_load_lds((cg_void*)g, (lds_void*)l, 16, 0, 0);
}

#define VMCNT(n) asm volatile("s_waitcnt vmcnt(" #n ")" ::: "memory")
#define LGKM0()  asm volatile("s_waitcnt lgkmcnt(0)" ::: "memory")
#define FENCE()  asm volatile("" ::: "memory")

// ---------------- Kernel 1: rowwise masked quantization ----------------
// Writes XQT in k-tiled swizzled layout: tile ks (16 KB) holds rows 0..255 x
// 64 B of k; within a row the 16B chunk c is stored at slot s = c ^ ((row>>1)&3).
__global__ __launch_bounds__(256) void oal_quant(
    const float* __restrict__ x, const int* __restrict__ oidx,
    int8_t* __restrict__ xqt, float* __restrict__ xs, float* __restrict__ xo)
{
    const int row = blockIdx.x;
    const int tid = threadIdx.x;
    __shared__ unsigned char flags[IN_F];
    __shared__ float wmax[4];
    __shared__ float s_scale;

    const float* xr = x + (size_t)row * IN_F;
    float4 v[4];
    const float4* xp = reinterpret_cast<const float4*>(xr + tid * 16);
    #pragma unroll
    for (int i = 0; i < 4; ++i) v[i] = xp[i];

    *reinterpret_cast<uint4*>(&flags[tid * 16]) = make_uint4(0u, 0u, 0u, 0u);
    __syncthreads();
    if (tid < N_OUT) flags[oidx[tid]] = 1;
    __syncthreads();

    uint4 f = *reinterpret_cast<const uint4*>(&flags[tid * 16]);
    unsigned int fw[4] = { f.x, f.y, f.z, f.w };
    float vals[16];
    #pragma unroll
    for (int i = 0; i < 4; ++i) {
        vals[i*4+0] = ((fw[i]      ) & 255u) ? 0.0f : v[i].x;
        vals[i*4+1] = ((fw[i] >>  8) & 255u) ? 0.0f : v[i].y;
        vals[i*4+2] = ((fw[i] >> 16) & 255u) ? 0.0f : v[i].z;
        vals[i*4+3] = ((fw[i] >> 24) & 255u) ? 0.0f : v[i].w;
    }

    float m = 0.0f;
    #pragma unroll
    for (int i = 0; i < 16; ++i) m = fmaxf(m, fabsf(vals[i]));
    #pragma unroll
    for (int off = 32; off > 0; off >>= 1) m = fmaxf(m, __shfl_xor(m, off, 64));
    const int lane = tid & 63, wid = tid >> 6;
    if (lane == 0) wmax[wid] = m;
    __syncthreads();
    if (tid == 0) {
        float s = fmaxf(fmaxf(wmax[0], wmax[1]), fmaxf(wmax[2], wmax[3]));
        s_scale = s;
        xs[row] = s;
    }
    __syncthreads();
    const float safe = fmaxf(s_scale, 1e-8f);

    int q[16];
    #pragma unroll
    for (int i = 0; i < 16; ++i) {
        float t = vals[i] / safe * 127.0f;        // exact reference order
        t = fminf(127.0f, fmaxf(-127.0f, rintf(t)));
        q[i] = (int)t;
    }
    uint4 packed;
    unsigned int* pw = &packed.x;
    #pragma unroll
    for (int i = 0; i < 4; ++i)
        pw[i] = (unsigned)(q[i*4] & 255) | ((unsigned)(q[i*4+1] & 255) << 8)
              | ((unsigned)(q[i*4+2] & 255) << 16) | ((unsigned)(q[i*4+3] & 255) << 24);

    // swizzled tiled store: thread handles kstep ks = tid>>2, chunk c = tid&3
    const int ks = tid >> 2;
    const int c  = tid & 3;
    const int sw = c ^ ((row >> 1) & 3);
    *reinterpret_cast<uint4*>(xqt + (size_t)ks * TILE_A + row * 64 + sw * 16) = packed;

    if (tid < N_OUT) xo[row * N_OUT + tid] = xr[oidx[tid]];
}

// ---------------- Kernel 2: int8 MFMA GEMM, 64-phase LDS pipeline ----------------
// 256 blocks x 512 threads; block bn -> output cols [bn*16,+16), all 256 rows.
// Phase ks: stage A tile ks+2 via global_load_lds (3-slot ring) + weight tile
// ks+2 to regs; compute tile ks; counted vmcnt(3) (never drain); pack weight
// int32->int8 into packed-B ring for tile ks+1; lgkmcnt(0); raw s_barrier.
__global__ __launch_bounds__(512, 1) void oal_gemm(
    const int8_t* __restrict__ xqt, const int* __restrict__ wgt,
    const float* __restrict__ xs, const float* __restrict__ wscale,
    const float* __restrict__ ow, const float* __restrict__ bias,
    const float* __restrict__ xo, float* __restrict__ out)
{
    __shared__ __align__(16) int8_t As[3][TILE_A];   // 48 KB
    __shared__ __align__(16) int8_t Bp[3][1024];     // 3 KB packed int8 B

    const int bn = blockIdx.x;
    const int tid = threadIdx.x;
    const int lane = tid & 63;
    const int wv = tid >> 6;
    const int kof = lane >> 4;

    // A-fragment LDS read offsets (swizzled)
    const int r0 = wv * 32 + (lane & 15);
    const int r1 = r0 + 16;
    const int a0off = r0 * 64 + ((kof ^ ((r0 >> 1) & 3)) * 16);
    const int a1off = r1 * 64 + ((kof ^ ((r1 >> 1) & 3)) * 16);
    // B-fragment LDS read offset (swizzled)
    const int rb = lane & 15;
    const int boff = rb * 64 + ((kof ^ ((rb >> 1) & 3)) * 16);

    // A staging sources (XQT already swizzled -> linear copy per tile)
    const int8_t* asrc0 = xqt + (size_t)(wv * 64 + lane) * 16;
    const int8_t* asrc1 = xqt + (size_t)((8 + wv) * 64 + lane) * 16;

    // B staging: thread covers 2 consecutive int32 of the 16x64 tile
    const int brow = tid >> 5;
    const int bdw  = (2 * tid) & 63;
    const int* bsrc = wgt + (size_t)(bn * BN + brow) * IN_F + bdw;
    const int bpoff = brow * 64 + (((bdw >> 4) ^ ((brow >> 1) & 3)) * 16) + (bdw & 15);

    v4i acc0 = {0,0,0,0}, acc1 = {0,0,0,0};
    uint2 braw0, braw1;

    // ---- prologue: tiles 0 and 1 ----
    gll16(asrc0, &As[0][wv * 1024]);
    gll16(asrc1, &As[0][(8 + wv) * 1024]);
    braw0 = *reinterpret_cast<const uint2*>(bsrc);
    asrc0 += TILE_A; asrc1 += TILE_A; bsrc += 64;
    gll16(asrc0, &As[1][wv * 1024]);
    gll16(asrc1, &As[1][(8 + wv) * 1024]);
    braw1 = *reinterpret_cast<const uint2*>(bsrc);
    asrc0 += TILE_A; asrc1 += TILE_A; bsrc += 64;
    VMCNT(0);                       // prologue-only full drain (safe vs reordering)
    *reinterpret_cast<uint16_t*>(&Bp[0][bpoff]) =
        (uint16_t)((braw0.x & 255) | ((braw0.y & 255) << 8));
    LGKM0();
    __builtin_amdgcn_s_barrier();
    FENCE();

#define PHASE(SR, SS, SW, BIN, BOUT, STAGE, FINAL, VMN)                          \
    {                                                                            \
        if (STAGE) {                                                             \
            gll16(asrc0, &As[SS][wv * 1024]);                                    \
            gll16(asrc1, &As[SS][(8 + wv) * 1024]);                              \
            BIN = *reinterpret_cast<const uint2*>(bsrc);                         \
            asrc0 += TILE_A; asrc1 += TILE_A; bsrc += 64;                        \
        }                                                                        \
        v4i a0_ = *reinterpret_cast<const v4i*>(&As[SR][a0off]);                 \
        v4i a1_ = *reinterpret_cast<const v4i*>(&As[SR][a1off]);                 \
        v4i bv_ = *reinterpret_cast<const v4i*>(&Bp[SR][boff]);                  \
        acc0 = __builtin_amdgcn_mfma_i32_16x16x64_i8(a0_, bv_, acc0, 0, 0, 0);   \
        acc1 = __builtin_amdgcn_mfma_i32_16x16x64_i8(a1_, bv_, acc1, 0, 0, 0);   \
        if (!(FINAL)) {                                                          \
            VMCNT(VMN);                                                          \
            *reinterpret_cast<uint16_t*>(&Bp[SW][bpoff]) =                       \
                (uint16_t)((BOUT.x & 255) | ((BOUT.y & 255) << 8));              \
            LGKM0();                                                             \
            __builtin_amdgcn_s_barrier();                                        \
            FENCE();                                                             \
        }                                                                        \
    }

    // phases 0..59 (slots and reg parity cycle with period 6)
    for (int kb = 0; kb < 60; kb += 6) {
        PHASE(0,2,1, braw0, braw1, 1, 0, 3);
        PHASE(1,0,2, braw1, braw0, 1, 0, 3);
        PHASE(2,1,0, braw0, braw1, 1, 0, 3);
        PHASE(0,2,1, braw1, braw0, 1, 0, 3);
        PHASE(1,0,2, braw0, braw1, 1, 0, 3);
        PHASE(2,1,0, braw1, braw0, 1, 0, 3);
    }
    // phases 60..63
    PHASE(0,2,1, braw0, braw1, 1, 0, 3);   // ks=60 stages tile 62
    PHASE(1,0,2, braw1, braw0, 1, 0, 3);   // ks=61 stages tile 63
    PHASE(2,0,0, braw0, braw1, 0, 0, 0);   // ks=62: drain, pack tile 63 -> Bp[0]
    PHASE(0,0,0, braw0, braw0, 0, 1, 0);   // ks=63: compute only
#undef PHASE

    // ---------------- epilogue ----------------
    const int ocol = bn * BN + (lane & 15);
    const float wsc = wscale[ocol] * (1.0f / 16129.0f);  // /127^2
    const float bo  = bias[ocol];
    float4 owr[8];
    const float4* owp = reinterpret_cast<const float4*>(ow + (size_t)ocol * N_OUT);
    #pragma unroll
    for (int i = 0; i < 8; ++i) owr[i] = owp[i];

    const int rbase = kof * 4;
    const int mrow = wv * 32;
    #pragma unroll
    for (int mt = 0; mt < 2; ++mt) {
        v4i a = mt ? acc1 : acc0;
        #pragma unroll
        for (int r = 0; r < 4; ++r) {
            const int t = mrow + mt * 16 + rbase + r;
            const float4* xr4 = reinterpret_cast<const float4*>(xo + (size_t)t * N_OUT);
            float dot = 0.0f;
            #pragma unroll
            for (int j = 0; j < 8; ++j) {
                float4 o4 = owr[j];
                float4 x4 = xr4[j];
                dot += x4.x*o4.x + x4.y*o4.y + x4.z*o4.z + x4.w*o4.w;
            }
            out[(size_t)t * OUT_F + ocol] = (float)a[r] * (xs[t] * wsc) + bo + dot;
        }
    }
}

extern "C" void kernel_launch(void* const* d_in, const int* in_sizes, int n_in,
                              void* d_out, int out_size, void* d_ws, size_t ws_size,
                              hipStream_t stream) {
    const float* x      = (const float*)d_in[0];
    const int*   w      = (const int*)  d_in[1];
    const float* wscale = (const float*)d_in[2];
    const int*   oidx   = (const int*)  d_in[3];
    const float* ow     = (const float*)d_in[4];
    const float* bias   = (const float*)d_in[5];
    float* out = (float*)d_out;

    int8_t* xqt = (int8_t*)d_ws;
    float*  xs  = (float*)((char*)d_ws + (size_t)TOK * IN_F);
    float*  xo  = (float*)((char*)d_ws + (size_t)TOK * IN_F + 1024);

    oal_quant<<<TOK, 256, 0, stream>>>(x, oidx, xqt, xs, xo);
    oal_gemm<<<OUT_F / BN, 512, 0, stream>>>(xqt, w, xs, wscale, ow, bias, xo, out);
}